// Round 10
// baseline (287.539 us; speedup 1.0000x reference)
//
#include <hip/hip_runtime.h>
#include <hip/hip_fp16.h>
#include <stdint.h>

// Luong attention: out = softmax(Q K^T) K,  B=16, Tq=Tk=D=1024, fp32 in/out.
//
// Swizzled fragment-major layout (per 1024x1024 batch):
//   addr_halfs(r, c) = (c>>5)*32768 + r*32 + (c&31)
// so a 16x16x32 MFMA fragment read (lane = n16*32 + quad*8) is a contiguous
// 1KB wave-coalesced global_load_dwordx4.
//
// R13 (passed, 278us total; fused 145us): fused scores+softmax+ctx, P via
// LDS. Counters: MfmaUtil 18.6% == per-CU L2-service model (64KB/iter @ ~56
// B/cyc/CU vs 310cyc MFMA), but phases run ~2x even that floor. Suspects:
// (a) all CUs of an XCD read the SAME 64KB chunk per iteration in lockstep
// (L2 bank hotspot), (b) load->wait->MFMA serialization with zero VGPR
// headroom (VGPR_Count pinned at 128).
// R14 (this): two zero-register-cost scheduling fixes on the R13 structure:
//  1. per-block K-loop ROTATION (j=(dcl+rot)&15, rot=idx&31): concurrent
//     blocks on an XCD walk different chunks -> de-hotspot L2 banks.
//  2. rolling prefetch: bf[cb] is reloaded for the NEXT iteration right
//     after its last MFMA use (single buffer, allocator reuses regs);
//     prologue bf loads issue BEFORE the staging/P-write barriers (global
//     reads are barrier-independent), overlapping LDS fill with L2 fetch,
//     including across the QK phase boundary and the PV pass boundary.
//
// [cvt]   enc f32 -> encsw (swizzled) + encTsw (LDS 64x64 transpose, swizzled)
// [fused] stage Q->LDS fp16 (2 phases); S = Q K^T; softmax; P->LDS (2 halves);
//         out = P @ enc (A from LDS, B from encTsw); store out fp32.
// Workspace: encsw 32MiB | encTsw 32MiB = 64MiB.

typedef _Float16 half_t;
typedef __attribute__((ext_vector_type(8))) _Float16 f16x8;
typedef __attribute__((ext_vector_type(2))) _Float16 f16x2;
typedef __attribute__((ext_vector_type(4))) float f32x4;

// ---------------------------------------------------------------------------
// Kernel 1: enc fp32 -> fp16 swizzled (direct + transposed).
// grid (rt=16, ct=16, b=16), block 256.
// ---------------------------------------------------------------------------
__global__ __launch_bounds__(256) void cvt_kernel(
    const float* __restrict__ enc,
    half_t* __restrict__ encsw, half_t* __restrict__ encTsw) {
    __shared__ half_t lt[64 * 65];  // pad 65: conflict-free transpose
    const int b = blockIdx.z;
    const int rt = blockIdx.x, ct = blockIdx.y;
    const int t = threadIdx.x;
    const int r = t >> 2;           // local row 0..63
    const int c0 = (t & 3) << 4;    // local col segment {0,16,32,48}
    const size_t bofs = (size_t)b << 20;

    const float* src = enc + bofs + (size_t)(rt * 64 + r) * 1024 + ct * 64 + c0;
    const float4* s4 = (const float4*)src;
    const float4 f0 = s4[0];
    const float4 f1 = s4[1];
    const float4 f2 = s4[2];
    const float4 f3 = s4[3];

    union { half_t h[16]; uint4 q[2]; } v;
    v.h[0]  = (half_t)f0.x; v.h[1]  = (half_t)f0.y;
    v.h[2]  = (half_t)f0.z; v.h[3]  = (half_t)f0.w;
    v.h[4]  = (half_t)f1.x; v.h[5]  = (half_t)f1.y;
    v.h[6]  = (half_t)f1.z; v.h[7]  = (half_t)f1.w;
    v.h[8]  = (half_t)f2.x; v.h[9]  = (half_t)f2.y;
    v.h[10] = (half_t)f2.z; v.h[11] = (half_t)f2.w;
    v.h[12] = (half_t)f3.x; v.h[13] = (half_t)f3.y;
    v.h[14] = (half_t)f3.z; v.h[15] = (half_t)f3.w;

    // direct swizzled write: element (gr, gc+i) -> (gc>>5)*32768 + gr*32 + (gc&31) + i
    {
        const int gr = rt * 64 + r, gc = ct * 64 + c0;
        half_t* dst = encsw + bofs
                      + (size_t)(gc >> 5) * 32768 + gr * 32 + (gc & 31);
        ((uint4*)dst)[0] = v.q[0];
        ((uint4*)dst)[1] = v.q[1];
    }

#pragma unroll
    for (int i = 0; i < 16; ++i) lt[r * 65 + c0 + i] = v.h[i];
    __syncthreads();
    // thread now holds (key = rt*64 + c0 + i, d = ct*64 + r), keys contiguous
    union { half_t h[16]; uint4 q[2]; } w;
#pragma unroll
    for (int i = 0; i < 16; ++i) w.h[i] = lt[(c0 + i) * 65 + r];
    const int gk = rt * 64 + c0, gd = ct * 64 + r;
    half_t* dstT = encTsw + bofs
                   + (size_t)(gk >> 5) * 32768 + gd * 32 + (gk & 31);
    ((uint4*)dstT)[0] = w.q[0];
    ((uint4*)dstT)[1] = w.q[1];
}

// ---------------------------------------------------------------------------
// Kernel 2 (FUSED): scores + softmax + context. grid 256 x 512 thr (8 waves).
// Block = (batch, 64 q-rows). QK: wave w owns keys {h*512 + w*64}, h=0,1,
// acc[4][8]. PV: wave w owns out-cols d = w*128..+128, accv[4][8].
// Q and P time-share one 64KiB LDS buffer (identical swizzled layout; aoff[]
// serves both). K-loops rotated per block + rolling bf prefetch (R14).
// ---------------------------------------------------------------------------
__global__ __launch_bounds__(512, 2) void fused_kernel(
    const float* __restrict__ dec, const half_t* __restrict__ encsw,
    const half_t* __restrict__ encTsw, float* __restrict__ out) {
    // 64 KiB: qlds for QK, then red/redg (softmax), then plds for PV.
    __shared__ __align__(16) unsigned char smem[65536];
    half_t* qlds = (half_t*)smem;           // [16 chunks][64 rows][32 cols]
    half_t* plds = (half_t*)smem;           // same region, same layout (P)
    float* red = (float*)smem;              // [512]
    float* redg = (float*)(smem + 2048);    // [64]

    const int l = blockIdx.x;
    const int xcd = l & 7, idx = l >> 3;
    const int b = xcd + ((idx >> 4) << 3);   // 2 batches per XCD: enc* L2-resident
    const int qbase = (idx & 15) * 64;
    const int rot = idx & 31;                // per-block K-loop rotation (R14)

    const int tid = threadIdx.x;
    const int w = tid >> 6, lane = tid & 63, quad = lane >> 4, n16 = lane & 15;
    const int laneoff = n16 * 32 + quad * 8;   // frag lane offset within 1KB chunk
    const size_t bofs = (size_t)b << 20;

    // staging decomposition (both phases): 8 threads per row
    const int sr = tid >> 3;       // 0..63 local row
    const int sp = tid & 7;        // 0..7
    const int sg = (sr >> 1) & 3;  // slot-XOR key
    const float* srcrow = dec + bofs + (size_t)(qbase + sr) * 1024;

    // frag-read LDS offsets (halfs): row lr = rb*16+n16, slot quad^g
    int aoff[4];
#pragma unroll
    for (int rb = 0; rb < 4; ++rb) {
        const int lr = rb * 16 + n16;
        aoff[rb] = lr * 32 + ((quad ^ ((lr >> 1) & 3)) << 3);
    }

    f32x4 acc[4][8];
#pragma unroll
    for (int rb = 0; rb < 4; ++rb)
#pragma unroll
        for (int cf = 0; cf < 8; ++cf) acc[rb][cf] = (f32x4){0.f, 0.f, 0.f, 0.f};

    // QK prologue: preload bf for phase-0 first rotated chunk. Issued BEFORE
    // the staging barrier -> overlaps Q staging with the first L2 fetch.
    f16x8 bf[8];
    {
        const half_t* ec = encsw + bofs + (size_t)(rot & 15) * 32768;
#pragma unroll
        for (int cb = 0; cb < 8; ++cb)
            bf[cb] = *(const f16x8*)(
                ec + ((cb >> 2) * 512 + w * 64 + (cb & 3) * 16) * 32 + laneoff);
    }

    // ================= QK^T: S = Q K^T (2 staged phases) =================
#pragma unroll
    for (int ph = 0; ph < 2; ++ph) {
        if (ph) __syncthreads();   // all phase-0 qlds reads done before rewrite
#pragma unroll
        for (int k = 0; k < 4; ++k) {
            const int c0 = sp * 16 + k * 128;          // local col 0..511
            const float4* spv = (const float4*)(srcrow + ph * 512 + c0);
            const float4 a0 = spv[0], a1 = spv[1], a2 = spv[2], a3 = spv[3];
            union { half_t h[16]; uint4 q[2]; } u;
            u.h[0]  = (half_t)a0.x; u.h[1]  = (half_t)a0.y;
            u.h[2]  = (half_t)a0.z; u.h[3]  = (half_t)a0.w;
            u.h[4]  = (half_t)a1.x; u.h[5]  = (half_t)a1.y;
            u.h[6]  = (half_t)a1.z; u.h[7]  = (half_t)a1.w;
            u.h[8]  = (half_t)a2.x; u.h[9]  = (half_t)a2.y;
            u.h[10] = (half_t)a2.z; u.h[11] = (half_t)a2.w;
            u.h[12] = (half_t)a3.x; u.h[13] = (half_t)a3.y;
            u.h[14] = (half_t)a3.z; u.h[15] = (half_t)a3.w;
            const int chunk = c0 >> 5;                 // local chunk 0..15
            const int s0 = (c0 & 31) >> 3;             // {0,2}
            half_t* base = qlds + chunk * 2048 + sr * 32;
            ((uint4*)(base + ((s0 ^ sg) << 3)))[0] = u.q[0];
            ((uint4*)(base + (((s0 + 1) ^ sg) << 3)))[0] = u.q[1];
        }
        __syncthreads();

        for (int dcl = 0; dcl < 16; ++dcl) {
            const int j = (dcl + rot) & 15;            // rotated chunk (this iter)
            const int jn = (dcl + 1 + rot) & 15;       // next iter's chunk
            // next-iteration encsw chunk: cross the phase boundary on ph==0
            // (legal: global reads don't depend on the staging barrier);
            // final iteration of ph==1 harmlessly reloads the current chunk.
            const int dcn = (dcl < 15) ? (ph * 16 + jn)
                                       : (ph == 0 ? 16 + (rot & 15) : 16 + j);
            const half_t* ecn = encsw + bofs + (size_t)dcn * 32768;
            f16x8 af[4];
#pragma unroll
            for (int rb = 0; rb < 4; ++rb)
                af[rb] = *(const f16x8*)(qlds + j * 2048 + aoff[rb]);
#pragma unroll
            for (int cb = 0; cb < 8; ++cb) {
#pragma unroll
                for (int rb = 0; rb < 4; ++rb)
                    acc[rb][cb] = __builtin_amdgcn_mfma_f32_16x16x32_f16(
                        af[rb], bf[cb], acc[rb][cb], 0, 0, 0);
                // rolling prefetch: bf[cb] dead after its 4 MFMAs -> reload
                bf[cb] = *(const f16x8*)(
                    ecn + ((cb >> 2) * 512 + w * 64 + (cb & 3) * 16) * 32 + laneoff);
            }
        }
    }
    __syncthreads();  // qlds dead; red/redg alias it from here on

    // ======================= softmax (rows of S) =========================
    float mrow[4][4], srow[4][4];
#pragma unroll
    for (int rb = 0; rb < 4; ++rb)
#pragma unroll
        for (int r = 0; r < 4; ++r) {
            float m = -1e30f;
#pragma unroll
            for (int cf = 0; cf < 8; ++cf) m = fmaxf(m, acc[rb][cf][r]);
#pragma unroll
            for (int off = 1; off < 16; off <<= 1)
                m = fmaxf(m, __shfl_xor(m, off, 64));
            mrow[rb][r] = m;
        }
    if (n16 == 0) {
#pragma unroll
        for (int rb = 0; rb < 4; ++rb)
#pragma unroll
            for (int r = 0; r < 4; ++r)
                red[w * 64 + rb * 16 + quad * 4 + r] = mrow[rb][r];
    }
    __syncthreads();
    if (tid < 64) {
        float g = red[tid];
#pragma unroll
        for (int ww = 1; ww < 8; ++ww) g = fmaxf(g, red[ww * 64 + tid]);
        redg[tid] = g;
    }
    __syncthreads();
#pragma unroll
    for (int rb = 0; rb < 4; ++rb)
#pragma unroll
        for (int r = 0; r < 4; ++r) mrow[rb][r] = redg[rb * 16 + quad * 4 + r];
    __syncthreads();  // maxes consumed; red reused for sums

#pragma unroll
    for (int rb = 0; rb < 4; ++rb)
#pragma unroll
        for (int r = 0; r < 4; ++r) {
            float s = 0.f;
#pragma unroll
            for (int cf = 0; cf < 8; ++cf) {
                float p = __expf(acc[rb][cf][r] - mrow[rb][r]);
                acc[rb][cf][r] = p;
                s += p;
            }
#pragma unroll
            for (int off = 1; off < 16; off <<= 1) s += __shfl_xor(s, off, 64);
            srow[rb][r] = s;
        }
    if (n16 == 0) {
#pragma unroll
        for (int rb = 0; rb < 4; ++rb)
#pragma unroll
            for (int r = 0; r < 4; ++r)
                red[w * 64 + rb * 16 + quad * 4 + r] = srow[rb][r];
    }
    __syncthreads();
    if (tid < 64) {
        float g = 0.f;
#pragma unroll
        for (int ww = 0; ww < 8; ++ww) g += red[ww * 64 + tid];
        redg[tid] = g;
    }
    __syncthreads();
#pragma unroll
    for (int rb = 0; rb < 4; ++rb)
#pragma unroll
        for (int r = 0; r < 4; ++r)
            srow[rb][r] = 1.0f / redg[rb * 16 + quad * 4 + r];

    // Pack pass-1 P (key-half 1: cf 4..7) to fp16 so acc can die early.
    f16x2 hp[4][4][2];
#pragma unroll
    for (int rb = 0; rb < 4; ++rb)
#pragma unroll
        for (int cb = 0; cb < 4; ++cb)
#pragma unroll
            for (int pr = 0; pr < 2; ++pr) {
                f16x2 t;
                t[0] = (half_t)(acc[rb][4 + cb][2 * pr] * srow[rb][2 * pr]);
                t[1] = (half_t)(acc[rb][4 + cb][2 * pr + 1] * srow[rb][2 * pr + 1]);
                hp[rb][cb][pr] = t;
            }

    // PV prologue: preload bf for pass-0 first rotated chunk (overlaps the
    // P pass-0 LDS writes below; encTsw reads are barrier-independent).
    {
        const half_t* tc = encTsw + bofs + (size_t)(rot & 15) * 32768;
#pragma unroll
        for (int cb = 0; cb < 8; ++cb)
            bf[cb] = *(const f16x8*)(tc + (w * 128 + cb * 16) * 32 + laneoff);
    }
    __syncthreads();  // all redg reads done; plds (aliases red/redg) writable

    // ================= P pass 0: keys 0..511 -> plds =====================
#pragma unroll
    for (int rb = 0; rb < 4; ++rb)
#pragma unroll
        for (int cb = 0; cb < 4; ++cb) {
            const int cl = w * 64 + cb * 16 + n16;   // local key 0..511
            const int chunk = cl >> 5;
            const int l8 = (cl & 31) >> 3;           // logical slot
            const int c7 = cl & 7;
#pragma unroll
            for (int r = 0; r < 4; ++r) {
                const int lr = rb * 16 + quad * 4 + r;
                const int g = (lr >> 1) & 3;
                plds[chunk * 2048 + lr * 32 + (((l8 ^ g)) << 3) + c7] =
                    (half_t)(acc[rb][cb][r] * srow[rb][r]);
            }
        }
    __syncthreads();

    // ================= PV pass 0: out += P[:,0:512] @ enc ================
    f32x4 accv[4][8];
#pragma unroll
    for (int rb = 0; rb < 4; ++rb)
#pragma unroll
        for (int cb = 0; cb < 8; ++cb) accv[rb][cb] = (f32x4){0.f, 0.f, 0.f, 0.f};

    for (int kcl = 0; kcl < 16; ++kcl) {
        const int j = (kcl + rot) & 15;
        const int jn = (kcl + 1 + rot) & 15;
        const int kcn = (kcl < 15) ? jn : (16 + (rot & 15));  // last iter: prefetch pass 1
        const half_t* tcn = encTsw + bofs + (size_t)kcn * 32768;
        f16x8 af[4];
#pragma unroll
        for (int rb = 0; rb < 4; ++rb)
            af[rb] = *(const f16x8*)(plds + j * 2048 + aoff[rb]);
#pragma unroll
        for (int cb = 0; cb < 8; ++cb) {
#pragma unroll
            for (int rb = 0; rb < 4; ++rb)
                accv[rb][cb] = __builtin_amdgcn_mfma_f32_16x16x32_f16(
                    af[rb], bf[cb], accv[rb][cb], 0, 0, 0);
            bf[cb] = *(const f16x8*)(tcn + (w * 128 + cb * 16) * 32 + laneoff);
        }
    }
    __syncthreads();  // pass-0 plds reads done before rewrite

    // ================= P pass 1: keys 512..1023 -> plds ==================
#pragma unroll
    for (int rb = 0; rb < 4; ++rb)
#pragma unroll
        for (int cb = 0; cb < 4; ++cb) {
            const int cl = w * 64 + cb * 16 + n16;   // local key 0..511
            const int chunk = cl >> 5;
            const int l8 = (cl & 31) >> 3;
            const int c7 = cl & 7;
#pragma unroll
            for (int r = 0; r < 4; ++r) {
                const int lr = rb * 16 + quad * 4 + r;
                const int g = (lr >> 1) & 3;
                plds[chunk * 2048 + lr * 32 + (((l8 ^ g)) << 3) + c7] =
                    hp[rb][cb][r >> 1][r & 1];
            }
        }
    __syncthreads();

    // ================ PV pass 1: out += P[:,512:1024] @ enc ==============
    for (int kcl = 0; kcl < 16; ++kcl) {
        const int j = (kcl + rot) & 15;
        const int jn = (kcl + 1 + rot) & 15;
        const int kcn = (kcl < 15) ? (16 + jn) : (16 + j);   // clamp at end
        const half_t* tcn = encTsw + bofs + (size_t)kcn * 32768;
        f16x8 af[4];
#pragma unroll
        for (int rb = 0; rb < 4; ++rb)
            af[rb] = *(const f16x8*)(plds + j * 2048 + aoff[rb]);
#pragma unroll
        for (int cb = 0; cb < 8; ++cb) {
#pragma unroll
            for (int rb = 0; rb < 4; ++rb)
                accv[rb][cb] = __builtin_amdgcn_mfma_f32_16x16x32_f16(
                    af[rb], bf[cb], accv[rb][cb], 0, 0, 0);
            bf[cb] = *(const f16x8*)(tcn + (w * 128 + cb * 16) * 32 + laneoff);
        }
    }

    // ======================= store out (fp32) ============================
#pragma unroll
    for (int rb = 0; rb < 4; ++rb)
#pragma unroll
        for (int cb = 0; cb < 8; ++cb)
#pragma unroll
            for (int r = 0; r < 4; ++r) {
                const int row = qbase + rb * 16 + quad * 4 + r;
                const int col = w * 128 + cb * 16 + n16;
                out[bofs + (size_t)row * 1024 + col] = accv[rb][cb][r];
            }
}

extern "C" void kernel_launch(void* const* d_in, const int* in_sizes, int n_in,
                              void* d_out, int out_size, void* d_ws, size_t ws_size,
                              hipStream_t stream) {
    (void)in_sizes; (void)n_in; (void)out_size; (void)ws_size;
    const float* dec = (const float*)d_in[0];   // decoder_hidden  [16,1024,1024] f32
    const float* enc = (const float*)d_in[1];   // encoder_outputs [16,1024,1024] f32
    float* out = (float*)d_out;

    // workspace: encsw | encTsw, 32MiB each (64MiB total)
    half_t* encsw  = (half_t*)d_ws;
    half_t* encTsw = encsw + ((size_t)16 << 20);

    cvt_kernel<<<dim3(16, 16, 16), 256, 0, stream>>>(enc, encsw, encTsw);
    fused_kernel<<<dim3(256), 512, 0, stream>>>(dec, encsw, encTsw, out);
}

// Round 11
// 280.866 us; speedup vs baseline: 1.0238x; 1.0238x over previous
//
#include <hip/hip_runtime.h>
#include <hip/hip_fp16.h>
#include <stdint.h>

// Luong attention: out = softmax(Q K^T) K,  B=16, Tq=Tk=D=1024, fp32 in/out.
//
// Swizzled fragment-major layout (per 1024x1024 batch):
//   addr_halfs(r, c) = (c>>5)*32768 + r*32 + (c&31)
// so a 16x16x32 MFMA fragment read (lane = n16*32 + quad*8) is a contiguous
// 1KB wave-coalesced global_load_dwordx4.
//
// R13 (fused 145us): MfmaUtil 18.6%, loops ~3x over the L2-service floor.
// R14 (rotation + rolling prefetch): REGRESSION 151us, FETCH 101->136MB.
//   Lesson: lockstep chunk reads across blocks were GOOD (one fetch serves
//   all); rotation destroyed that. Prefetch bought 0 at 128 VGPR. Reverted.
// R15 theory: per-XCD working set = encsw 4MB + encTsw 4MB + dec stream
//   + out write-allocate >> 4MB L2 -> B-operands served by L3 (high latency,
//   1/3 BW) -> the 3x gap. Fix: make the STREAMING data bypass L2:
//   dec staging loads + out stores become nontemporal. enc* then fits L2
//   phase-wise (QK: encsw 4MB; PV: encTsw 4MB). Zero structural cost.
//
// [cvt]   enc f32 -> encsw (swizzled) + encTsw (LDS 64x64 transpose, swizzled)
// [fused] stage Q->LDS fp16 (2 phases, NT loads); S = Q K^T; softmax;
//         P->LDS (2 halves); out = P @ enc (B from encTsw); NT store out.
// Workspace: encsw 32MiB | encTsw 32MiB = 64MiB.

typedef _Float16 half_t;
typedef __attribute__((ext_vector_type(8))) _Float16 f16x8;
typedef __attribute__((ext_vector_type(2))) _Float16 f16x2;
typedef __attribute__((ext_vector_type(4))) float f32x4;

// ---------------------------------------------------------------------------
// Kernel 1: enc fp32 -> fp16 swizzled (direct + transposed).
// grid (rt=16, ct=16, b=16), block 256.
// ---------------------------------------------------------------------------
__global__ __launch_bounds__(256) void cvt_kernel(
    const float* __restrict__ enc,
    half_t* __restrict__ encsw, half_t* __restrict__ encTsw) {
    __shared__ half_t lt[64 * 65];  // pad 65: conflict-free transpose
    const int b = blockIdx.z;
    const int rt = blockIdx.x, ct = blockIdx.y;
    const int t = threadIdx.x;
    const int r = t >> 2;           // local row 0..63
    const int c0 = (t & 3) << 4;    // local col segment {0,16,32,48}
    const size_t bofs = (size_t)b << 20;

    const float* src = enc + bofs + (size_t)(rt * 64 + r) * 1024 + ct * 64 + c0;
    const float4* s4 = (const float4*)src;
    const float4 f0 = s4[0];
    const float4 f1 = s4[1];
    const float4 f2 = s4[2];
    const float4 f3 = s4[3];

    union { half_t h[16]; uint4 q[2]; } v;
    v.h[0]  = (half_t)f0.x; v.h[1]  = (half_t)f0.y;
    v.h[2]  = (half_t)f0.z; v.h[3]  = (half_t)f0.w;
    v.h[4]  = (half_t)f1.x; v.h[5]  = (half_t)f1.y;
    v.h[6]  = (half_t)f1.z; v.h[7]  = (half_t)f1.w;
    v.h[8]  = (half_t)f2.x; v.h[9]  = (half_t)f2.y;
    v.h[10] = (half_t)f2.z; v.h[11] = (half_t)f2.w;
    v.h[12] = (half_t)f3.x; v.h[13] = (half_t)f3.y;
    v.h[14] = (half_t)f3.z; v.h[15] = (half_t)f3.w;

    // direct swizzled write: element (gr, gc+i) -> (gc>>5)*32768 + gr*32 + (gc&31) + i
    {
        const int gr = rt * 64 + r, gc = ct * 64 + c0;
        half_t* dst = encsw + bofs
                      + (size_t)(gc >> 5) * 32768 + gr * 32 + (gc & 31);
        ((uint4*)dst)[0] = v.q[0];
        ((uint4*)dst)[1] = v.q[1];
    }

#pragma unroll
    for (int i = 0; i < 16; ++i) lt[r * 65 + c0 + i] = v.h[i];
    __syncthreads();
    // thread now holds (key = rt*64 + c0 + i, d = ct*64 + r), keys contiguous
    union { half_t h[16]; uint4 q[2]; } w;
#pragma unroll
    for (int i = 0; i < 16; ++i) w.h[i] = lt[(c0 + i) * 65 + r];
    const int gk = rt * 64 + c0, gd = ct * 64 + r;
    half_t* dstT = encTsw + bofs
                   + (size_t)(gk >> 5) * 32768 + gd * 32 + (gk & 31);
    ((uint4*)dstT)[0] = w.q[0];
    ((uint4*)dstT)[1] = w.q[1];
}

// ---------------------------------------------------------------------------
// Kernel 2 (FUSED): scores + softmax + context. grid 256 x 512 thr (8 waves).
// Block = (batch, 64 q-rows). QK: wave w owns keys {h*512 + w*64}, h=0,1,
// acc[4][8]. PV: wave w owns out-cols d = w*128..+128, accv[4][8].
// Q and P time-share one 64KiB LDS buffer (identical swizzled layout; aoff[]
// serves both). dec loads and out stores are NONTEMPORAL (R15).
// ---------------------------------------------------------------------------
__global__ __launch_bounds__(512, 2) void fused_kernel(
    const float* __restrict__ dec, const half_t* __restrict__ encsw,
    const half_t* __restrict__ encTsw, float* __restrict__ out) {
    // 64 KiB: qlds for QK, then red/redg (softmax), then plds for PV.
    __shared__ __align__(16) unsigned char smem[65536];
    half_t* qlds = (half_t*)smem;           // [16 chunks][64 rows][32 cols]
    half_t* plds = (half_t*)smem;           // same region, same layout (P)
    float* red = (float*)smem;              // [512]
    float* redg = (float*)(smem + 2048);    // [64]

    const int l = blockIdx.x;
    const int xcd = l & 7, idx = l >> 3;
    const int b = xcd + ((idx >> 4) << 3);   // 2 batches per XCD: enc* L2-resident
    const int qbase = (idx & 15) * 64;

    const int tid = threadIdx.x;
    const int w = tid >> 6, lane = tid & 63, quad = lane >> 4, n16 = lane & 15;
    const int laneoff = n16 * 32 + quad * 8;   // frag lane offset within 1KB chunk
    const size_t bofs = (size_t)b << 20;

    // staging decomposition (both phases): 8 threads per row
    const int sr = tid >> 3;       // 0..63 local row
    const int sp = tid & 7;        // 0..7
    const int sg = (sr >> 1) & 3;  // slot-XOR key
    const float* srcrow = dec + bofs + (size_t)(qbase + sr) * 1024;

    // frag-read LDS offsets (halfs): row lr = rb*16+n16, slot quad^g
    int aoff[4];
#pragma unroll
    for (int rb = 0; rb < 4; ++rb) {
        const int lr = rb * 16 + n16;
        aoff[rb] = lr * 32 + ((quad ^ ((lr >> 1) & 3)) << 3);
    }

    f32x4 acc[4][8];
#pragma unroll
    for (int rb = 0; rb < 4; ++rb)
#pragma unroll
        for (int cf = 0; cf < 8; ++cf) acc[rb][cf] = (f32x4){0.f, 0.f, 0.f, 0.f};

    // ================= QK^T: S = Q K^T (2 staged phases) =================
#pragma unroll
    for (int ph = 0; ph < 2; ++ph) {
        if (ph) __syncthreads();   // all phase-0 qlds reads done before rewrite
#pragma unroll
        for (int k = 0; k < 4; ++k) {
            const int c0 = sp * 16 + k * 128;          // local col 0..511
            // NONTEMPORAL: dec is read-once -> don't allocate L2 lines (R15)
            const f32x4* spv = (const f32x4*)(srcrow + ph * 512 + c0);
            const f32x4 a0 = __builtin_nontemporal_load(spv + 0);
            const f32x4 a1 = __builtin_nontemporal_load(spv + 1);
            const f32x4 a2 = __builtin_nontemporal_load(spv + 2);
            const f32x4 a3 = __builtin_nontemporal_load(spv + 3);
            union { half_t h[16]; uint4 q[2]; } u;
            u.h[0]  = (half_t)a0[0]; u.h[1]  = (half_t)a0[1];
            u.h[2]  = (half_t)a0[2]; u.h[3]  = (half_t)a0[3];
            u.h[4]  = (half_t)a1[0]; u.h[5]  = (half_t)a1[1];
            u.h[6]  = (half_t)a1[2]; u.h[7]  = (half_t)a1[3];
            u.h[8]  = (half_t)a2[0]; u.h[9]  = (half_t)a2[1];
            u.h[10] = (half_t)a2[2]; u.h[11] = (half_t)a2[3];
            u.h[12] = (half_t)a3[0]; u.h[13] = (half_t)a3[1];
            u.h[14] = (half_t)a3[2]; u.h[15] = (half_t)a3[3];
            const int chunk = c0 >> 5;                 // local chunk 0..15
            const int s0 = (c0 & 31) >> 3;             // {0,2}
            half_t* base = qlds + chunk * 2048 + sr * 32;
            ((uint4*)(base + ((s0 ^ sg) << 3)))[0] = u.q[0];
            ((uint4*)(base + (((s0 + 1) ^ sg) << 3)))[0] = u.q[1];
        }
        __syncthreads();

        for (int dcl = 0; dcl < 16; ++dcl) {
            const int dc = ph * 16 + dcl;
            const half_t* ec = encsw + bofs + (size_t)dc * 32768;
            f16x8 bf[8];
#pragma unroll
            for (int h = 0; h < 2; ++h)
#pragma unroll
                for (int cb = 0; cb < 4; ++cb)
                    bf[h * 4 + cb] = *(const f16x8*)(
                        ec + (h * 512 + w * 64 + cb * 16) * 32 + laneoff);
            f16x8 af[4];
#pragma unroll
            for (int rb = 0; rb < 4; ++rb)
                af[rb] = *(const f16x8*)(qlds + dcl * 2048 + aoff[rb]);
#pragma unroll
            for (int rb = 0; rb < 4; ++rb)
#pragma unroll
                for (int cf = 0; cf < 8; ++cf)
                    acc[rb][cf] = __builtin_amdgcn_mfma_f32_16x16x32_f16(
                        af[rb], bf[cf], acc[rb][cf], 0, 0, 0);
        }
    }
    __syncthreads();  // qlds dead; red/redg alias it from here on

    // ======================= softmax (rows of S) =========================
    float mrow[4][4], srow[4][4];
#pragma unroll
    for (int rb = 0; rb < 4; ++rb)
#pragma unroll
        for (int r = 0; r < 4; ++r) {
            float m = -1e30f;
#pragma unroll
            for (int cf = 0; cf < 8; ++cf) m = fmaxf(m, acc[rb][cf][r]);
#pragma unroll
            for (int off = 1; off < 16; off <<= 1)
                m = fmaxf(m, __shfl_xor(m, off, 64));
            mrow[rb][r] = m;
        }
    if (n16 == 0) {
#pragma unroll
        for (int rb = 0; rb < 4; ++rb)
#pragma unroll
            for (int r = 0; r < 4; ++r)
                red[w * 64 + rb * 16 + quad * 4 + r] = mrow[rb][r];
    }
    __syncthreads();
    if (tid < 64) {
        float g = red[tid];
#pragma unroll
        for (int ww = 1; ww < 8; ++ww) g = fmaxf(g, red[ww * 64 + tid]);
        redg[tid] = g;
    }
    __syncthreads();
#pragma unroll
    for (int rb = 0; rb < 4; ++rb)
#pragma unroll
        for (int r = 0; r < 4; ++r) mrow[rb][r] = redg[rb * 16 + quad * 4 + r];
    __syncthreads();  // maxes consumed; red reused for sums

#pragma unroll
    for (int rb = 0; rb < 4; ++rb)
#pragma unroll
        for (int r = 0; r < 4; ++r) {
            float s = 0.f;
#pragma unroll
            for (int cf = 0; cf < 8; ++cf) {
                float p = __expf(acc[rb][cf][r] - mrow[rb][r]);
                acc[rb][cf][r] = p;
                s += p;
            }
#pragma unroll
            for (int off = 1; off < 16; off <<= 1) s += __shfl_xor(s, off, 64);
            srow[rb][r] = s;
        }
    if (n16 == 0) {
#pragma unroll
        for (int rb = 0; rb < 4; ++rb)
#pragma unroll
            for (int r = 0; r < 4; ++r)
                red[w * 64 + rb * 16 + quad * 4 + r] = srow[rb][r];
    }
    __syncthreads();
    if (tid < 64) {
        float g = 0.f;
#pragma unroll
        for (int ww = 0; ww < 8; ++ww) g += red[ww * 64 + tid];
        redg[tid] = g;
    }
    __syncthreads();
#pragma unroll
    for (int rb = 0; rb < 4; ++rb)
#pragma unroll
        for (int r = 0; r < 4; ++r)
            srow[rb][r] = 1.0f / redg[rb * 16 + quad * 4 + r];

    // Pack pass-1 P (key-half 1: cf 4..7) to fp16 so acc can die early.
    f16x2 hp[4][4][2];
#pragma unroll
    for (int rb = 0; rb < 4; ++rb)
#pragma unroll
        for (int cb = 0; cb < 4; ++cb)
#pragma unroll
            for (int pr = 0; pr < 2; ++pr) {
                f16x2 t;
                t[0] = (half_t)(acc[rb][4 + cb][2 * pr] * srow[rb][2 * pr]);
                t[1] = (half_t)(acc[rb][4 + cb][2 * pr + 1] * srow[rb][2 * pr + 1]);
                hp[rb][cb][pr] = t;
            }
    __syncthreads();  // all redg reads done; plds (aliases red/redg) writable

    // ================= P pass 0: keys 0..511 -> plds =====================
#pragma unroll
    for (int rb = 0; rb < 4; ++rb)
#pragma unroll
        for (int cb = 0; cb < 4; ++cb) {
            const int cl = w * 64 + cb * 16 + n16;   // local key 0..511
            const int chunk = cl >> 5;
            const int l8 = (cl & 31) >> 3;           // logical slot
            const int c7 = cl & 7;
#pragma unroll
            for (int r = 0; r < 4; ++r) {
                const int lr = rb * 16 + quad * 4 + r;
                const int g = (lr >> 1) & 3;
                plds[chunk * 2048 + lr * 32 + (((l8 ^ g)) << 3) + c7] =
                    (half_t)(acc[rb][cb][r] * srow[rb][r]);
            }
        }
    __syncthreads();

    // ================= PV pass 0: out += P[:,0:512] @ enc ================
    f32x4 accv[4][8];
#pragma unroll
    for (int rb = 0; rb < 4; ++rb)
#pragma unroll
        for (int cb = 0; cb < 8; ++cb) accv[rb][cb] = (f32x4){0.f, 0.f, 0.f, 0.f};

    for (int kcl = 0; kcl < 16; ++kcl) {
        const half_t* tc = encTsw + bofs + (size_t)kcl * 32768;
        f16x8 bf[8];
#pragma unroll
        for (int cb = 0; cb < 8; ++cb)
            bf[cb] = *(const f16x8*)(tc + (w * 128 + cb * 16) * 32 + laneoff);
        f16x8 af[4];
#pragma unroll
        for (int rb = 0; rb < 4; ++rb)
            af[rb] = *(const f16x8*)(plds + kcl * 2048 + aoff[rb]);
#pragma unroll
        for (int rb = 0; rb < 4; ++rb)
#pragma unroll
            for (int cb = 0; cb < 8; ++cb)
                accv[rb][cb] = __builtin_amdgcn_mfma_f32_16x16x32_f16(
                    af[rb], bf[cb], accv[rb][cb], 0, 0, 0);
    }
    __syncthreads();  // pass-0 plds reads done before rewrite

    // ================= P pass 1: keys 512..1023 -> plds ==================
#pragma unroll
    for (int rb = 0; rb < 4; ++rb)
#pragma unroll
        for (int cb = 0; cb < 4; ++cb) {
            const int cl = w * 64 + cb * 16 + n16;   // local key 0..511
            const int chunk = cl >> 5;
            const int l8 = (cl & 31) >> 3;
            const int c7 = cl & 7;
#pragma unroll
            for (int r = 0; r < 4; ++r) {
                const int lr = rb * 16 + quad * 4 + r;
                const int g = (lr >> 1) & 3;
                plds[chunk * 2048 + lr * 32 + (((l8 ^ g)) << 3) + c7] =
                    hp[rb][cb][r >> 1][r & 1];
            }
        }
    __syncthreads();

    // ================ PV pass 1: out += P[:,512:1024] @ enc ==============
    for (int kcl = 0; kcl < 16; ++kcl) {
        const half_t* tc = encTsw + bofs + (size_t)(16 + kcl) * 32768;
        f16x8 bf[8];
#pragma unroll
        for (int cb = 0; cb < 8; ++cb)
            bf[cb] = *(const f16x8*)(tc + (w * 128 + cb * 16) * 32 + laneoff);
        f16x8 af[4];
#pragma unroll
        for (int rb = 0; rb < 4; ++rb)
            af[rb] = *(const f16x8*)(plds + kcl * 2048 + aoff[rb]);
#pragma unroll
        for (int rb = 0; rb < 4; ++rb)
#pragma unroll
            for (int cb = 0; cb < 8; ++cb)
                accv[rb][cb] = __builtin_amdgcn_mfma_f32_16x16x32_f16(
                    af[rb], bf[cb], accv[rb][cb], 0, 0, 0);
    }

    // ============ store out (fp32, NONTEMPORAL: no L2 allocate) ==========
#pragma unroll
    for (int rb = 0; rb < 4; ++rb)
#pragma unroll
        for (int cb = 0; cb < 8; ++cb)
#pragma unroll
            for (int r = 0; r < 4; ++r) {
                const int row = qbase + rb * 16 + quad * 4 + r;
                const int col = w * 128 + cb * 16 + n16;
                __builtin_nontemporal_store(
                    accv[rb][cb][r], &out[bofs + (size_t)row * 1024 + col]);
            }
}

extern "C" void kernel_launch(void* const* d_in, const int* in_sizes, int n_in,
                              void* d_out, int out_size, void* d_ws, size_t ws_size,
                              hipStream_t stream) {
    (void)in_sizes; (void)n_in; (void)out_size; (void)ws_size;
    const float* dec = (const float*)d_in[0];   // decoder_hidden  [16,1024,1024] f32
    const float* enc = (const float*)d_in[1];   // encoder_outputs [16,1024,1024] f32
    float* out = (float*)d_out;

    // workspace: encsw | encTsw, 32MiB each (64MiB total)
    half_t* encsw  = (half_t*)d_ws;
    half_t* encTsw = encsw + ((size_t)16 << 20);

    cvt_kernel<<<dim3(16, 16, 16), 256, 0, stream>>>(enc, encsw, encTsw);
    fused_kernel<<<dim3(256), 512, 0, stream>>>(dec, encsw, encTsw, out);
}